// Round 6
// baseline (442.913 us; speedup 1.0000x reference)
//
#include <hip/hip_runtime.h>
#include <hip/hip_bf16.h>
#include <cstdint>
#include <cstddef>

#define EPS 1e-8f
#define H_T 2.0794415416798357f /* ln(8) */
#define NUM_MARKED 4194304.0f   /* B*K: is_event is exactly one-hot over T */

typedef __attribute__((ext_vector_type(8))) short bf16x8;
typedef __attribute__((ext_vector_type(4))) float f32x4;

__device__ __forceinline__ unsigned short f2bf(float f) {
    union { float f; unsigned u; } v; v.f = f;
    unsigned r = v.u + 0x7fffu + ((v.u >> 16) & 1u);
    return (unsigned short)(r >> 16);
}

__device__ __forceinline__ void gl_lds16(const void* g, void* l) {
    __builtin_amdgcn_global_load_lds((const __attribute__((address_space(1))) unsigned int*)g,
                                     (__attribute__((address_space(3))) unsigned int*)l, 16, 0, 0);
}

// 64x64 f32->bf16 transpose tile. float4 loads, LDS [64][65], ushort4 stores.
__device__ __forceinline__ void transpose64(const float* __restrict__ in,
                                            unsigned short* __restrict__ out,
                                            int R, int C, int bx, int by,
                                            int tid, float* tile) {
    int c0 = bx * 64, r0 = by * 64;
    int row = tid >> 4, c4 = tid & 15;
#pragma unroll
    for (int i = 0; i < 4; i++) {
        float4 v = *(const float4*)(in + (size_t)(r0 + row + i * 16) * C + c0 + c4 * 4);
        float* t = tile + (row + i * 16) * 65 + c4 * 4;
        t[0] = v.x; t[1] = v.y; t[2] = v.z; t[3] = v.w;
    }
    __syncthreads();
    int rq = tid & 15, ccb = tid >> 4;
#pragma unroll
    for (int i = 0; i < 4; i++) {
        int cc = ccb + i * 16;
        ushort4 o;
        o.x = f2bf(tile[(rq * 4 + 0) * 65 + cc]);
        o.y = f2bf(tile[(rq * 4 + 1) * 65 + cc]);
        o.z = f2bf(tile[(rq * 4 + 2) * 65 + cc]);
        o.w = f2bf(tile[(rq * 4 + 3) * 65 + cc]);
        *(ushort4*)(out + (size_t)(c0 + cc) * R + r0 + rq * 4) = o;
    }
}

// ---------------- prep_lite: featbf + W1T ----------------
__global__ __launch_bounds__(256) void prep_lite(const float* __restrict__ features,
                                                 const float* __restrict__ W1,
                                                 unsigned short* __restrict__ featbf,
                                                 unsigned short* __restrict__ W1T,
                                                 float* __restrict__ accum) {
    __shared__ float tile[64 * 65];
    int bid = blockIdx.x, tid = threadIdx.x;
    if (bid < 192) {
        if (bid == 0 && tid < 8) accum[tid] = 0.0f;
        int i = (bid * 256 + tid) * 8;
        float4 a = *(const float4*)(features + i);
        float4 b = *(const float4*)(features + i + 4);
        ushort4 o0, o1;
        o0.x = f2bf(a.x); o0.y = f2bf(a.y); o0.z = f2bf(a.z); o0.w = f2bf(a.w);
        o1.x = f2bf(b.x); o1.y = f2bf(b.y); o1.z = f2bf(b.z); o1.w = f2bf(b.w);
        *(ushort4*)(featbf + i) = o0;
        *(ushort4*)(featbf + i + 4) = o1;
        return;
    }
    int b = bid - 192;
    transpose64(W1, W1T, 768, 4096, b & 63, b >> 6, tid, tile);
}

// ---------------- mid_kernel: GEMM1+bias || compress stream || W2^T ----------------
// grid: [0,512) gemm_bias | [512,1536) compress (1 block per half-b) | [1536,2560) W2^T
// R6 compress redesign (R5 post-mortem: 2.1 TB/s, VALU 5%, VGPR 48 ->
// 4096 short-lived blocks each opening 16 concurrent 4KB streams = DRAM/L2
// stream thrash + compiler-serialized loads):
//   1024 blocks, each owns 4096 consecutive k's of one b -> per t-slab the
//   block reads a 16KB sequential run (4 segs x 4KB). t-loop manually
//   double-buffered with STATIC even/odd register sets (rule #20) so ~8
//   loads stay in flight while the previous slab is consumed. 16 k's of
//   accumulators per thread.
__global__ __launch_bounds__(256) void mid_kernel(const unsigned short* __restrict__ A,   // featbf 512x768
                                                  const unsigned short* __restrict__ BT,  // W1T 4096x768
                                                  const float* __restrict__ bias,         // b1
                                                  float* __restrict__ C,                  // xbuf 512x4096
                                                  const float* __restrict__ W2,
                                                  unsigned short* __restrict__ W2T,
                                                  const int* __restrict__ is_event,
                                                  const int* __restrict__ is_cens,
                                                  const float* __restrict__ ratio,
                                                  unsigned char* __restrict__ packed,
                                                  float* __restrict__ ratio_sel) {
    __shared__ union {
        struct { unsigned short lA[64 * 40]; unsigned short lB[64 * 40]; } g;
        float tile[64 * 65];
    } sm;
    int bid = blockIdx.x, tid = threadIdx.x;

    if (bid >= 1536) {
        int b = bid - 1536;
        transpose64(W2, W2T, 512, 8192, b & 127, b >> 7, tid, sm.tile);
        return;
    }
    if (bid >= 512) {
        const int NK = 8192;
        int c = bid - 512;                 // [0,1024)
        int b = c >> 1, half = c & 1;
        const int*   evbase  = is_event + (size_t)b * 8 * NK + half * 4096;
        const float* rtbase  = ratio    + (size_t)b * 8 * NK + half * 4096;
        const int*   cenbase = is_cens  + (size_t)b * NK     + half * 4096;
        int off = tid * 4;

        int tev[4][4]; float rsl[4][4];
#pragma unroll
        for (int s = 0; s < 4; s++)
#pragma unroll
            for (int j = 0; j < 4; j++) { tev[s][j] = 0; rsl[s][j] = 0.f; }

        int4 c4[4];
#pragma unroll
        for (int s = 0; s < 4; s++) c4[s] = *(const int4*)(cenbase + s * 1024 + off);

        auto LOADT = [&](int t, int4 (&EV)[4], float4 (&RT)[4]) {
#pragma unroll
            for (int s = 0; s < 4; s++) {
                EV[s] = *(const int4*)(evbase + (size_t)t * NK + s * 1024 + off);
                RT[s] = *(const float4*)(rtbase + (size_t)t * NK + s * 1024 + off);
            }
        };
        auto CONS = [&](int t, int4 (&EV)[4], float4 (&RT)[4]) {
#pragma unroll
            for (int s = 0; s < 4; s++) {
                int   vv[4] = {EV[s].x, EV[s].y, EV[s].z, EV[s].w};
                float rr[4] = {RT[s].x, RT[s].y, RT[s].z, RT[s].w};
#pragma unroll
                for (int j = 0; j < 4; j++) {
                    bool e = vv[j] != 0;
                    tev[s][j] = e ? t : tev[s][j];
                    rsl[s][j] = e ? rr[j] : rsl[s][j];
                }
            }
        };

        int4 evA[4], evB[4]; float4 rtA[4], rtB[4];
        LOADT(0, evA, rtA);
#pragma unroll
        for (int tp = 0; tp < 8; tp += 2) {
            if (tp + 1 < 8) LOADT(tp + 1, evB, rtB);
            CONS(tp, evA, rtA);
            if (tp + 2 < 8) LOADT(tp + 2, evA, rtA);
            if (tp + 1 < 8) CONS(tp + 1, evB, rtB);
        }

#pragma unroll
        for (int s = 0; s < 4; s++) {
            int cc[4] = {c4[s].x, c4[s].y, c4[s].z, c4[s].w};
            uchar4 pk4;
            pk4.x = (unsigned char)(tev[s][0] | ((cc[0] != 0) << 3));
            pk4.y = (unsigned char)(tev[s][1] | ((cc[1] != 0) << 3));
            pk4.z = (unsigned char)(tev[s][2] | ((cc[2] != 0) << 3));
            pk4.w = (unsigned char)(tev[s][3] | ((cc[3] != 0) << 3));
            size_t oidx = (size_t)b * NK + half * 4096 + s * 1024 + off;
            *(uchar4*)(packed + oidx) = pk4;
            float4 rs4; rs4.x = rsl[s][0]; rs4.y = rsl[s][1]; rs4.z = rsl[s][2]; rs4.w = rsl[s][3];
            *(float4*)(ratio_sel + oidx) = rs4;
        }
        return;
    }

    // ---- gemm_bias: M=512, N=4096, K=768; 64x64 tile, 2x2 waves ----
    const int N = 4096, K = 768;
    int m0 = (bid & 7) * 64, n0 = (bid >> 3) * 64;
    int lane = tid & 63, wave = tid >> 6;
    int wm = wave >> 1, wn = wave & 1;
    int r = lane & 15, q = lane >> 4;

    f32x4 acc[2][2];
#pragma unroll
    for (int i = 0; i < 2; i++)
#pragma unroll
        for (int j = 0; j < 2; j++) acc[i][j] = (f32x4){0.f, 0.f, 0.f, 0.f};

    int ldrow = tid >> 2, ldc = (tid & 3) * 8;

    for (int kk = 0; kk < K; kk += 32) {
        uint4 av = *(const uint4*)(A + (size_t)(m0 + ldrow) * K + kk + ldc);
        uint4 bv = *(const uint4*)(BT + (size_t)(n0 + ldrow) * K + kk + ldc);
        __syncthreads();
        *(uint4*)(&sm.g.lA[ldrow * 40 + ldc]) = av;
        *(uint4*)(&sm.g.lB[ldrow * 40 + ldc]) = bv;
        __syncthreads();

        bf16x8 a0 = *(const bf16x8*)(&sm.g.lA[(wm * 32 + r) * 40 + q * 8]);
        bf16x8 a1 = *(const bf16x8*)(&sm.g.lA[(wm * 32 + 16 + r) * 40 + q * 8]);
        bf16x8 b0 = *(const bf16x8*)(&sm.g.lB[(wn * 32 + r) * 40 + q * 8]);
        bf16x8 b1 = *(const bf16x8*)(&sm.g.lB[(wn * 32 + 16 + r) * 40 + q * 8]);
        acc[0][0] = __builtin_amdgcn_mfma_f32_16x16x32_bf16(a0, b0, acc[0][0], 0, 0, 0);
        acc[0][1] = __builtin_amdgcn_mfma_f32_16x16x32_bf16(a0, b1, acc[0][1], 0, 0, 0);
        acc[1][0] = __builtin_amdgcn_mfma_f32_16x16x32_bf16(a1, b0, acc[1][0], 0, 0, 0);
        acc[1][1] = __builtin_amdgcn_mfma_f32_16x16x32_bf16(a1, b1, acc[1][1], 0, 0, 0);
    }

#pragma unroll
    for (int i = 0; i < 2; i++)
#pragma unroll
        for (int j = 0; j < 2; j++)
#pragma unroll
            for (int reg = 0; reg < 4; reg++) {
                int row = m0 + wm * 32 + i * 16 + q * 4 + reg;
                int col = n0 + wn * 32 + j * 16 + r;
                C[(size_t)row * N + col] = acc[i][j][reg] + bias[col];
            }
}

// ---------------- RMSNorm ----------------
__global__ __launch_bounds__(256) void rms_kernel(const float* __restrict__ x,
                                                  const float* __restrict__ norm_w,
                                                  unsigned short* __restrict__ xn) {
    int m = blockIdx.x;
    int tid = threadIdx.x;
    const float* row = x + (size_t)m * 512;
    float v0 = row[tid];
    float v1 = row[tid + 256];
    float ss = v0 * v0 + v1 * v1;
#pragma unroll
    for (int o = 32; o > 0; o >>= 1) ss += __shfl_down(ss, o);
    __shared__ float rs[4];
    __shared__ float scale_sh;
    int lane = tid & 63, wave = tid >> 6;
    if (lane == 0) rs[wave] = ss;
    __syncthreads();
    if (tid == 0) {
        float tot = rs[0] + rs[1] + rs[2] + rs[3];
        scale_sh = 1.0f / sqrtf(tot * (1.0f / 512.0f) + 1e-6f);
    }
    __syncthreads();
    float s = scale_sh;
    xn[(size_t)m * 512 + tid] = f2bf(v0 * s * norm_w[tid]);
    xn[(size_t)m * 512 + tid + 256] = f2bf(v1 * s * norm_w[tid + 256]);
}

// ---------------- GEMM2 + softmax/cumsum/loss, fused (unchanged from R5) ----------------
__global__ __launch_bounds__(256, 2) void gemm_loss(const unsigned short* __restrict__ A,
                                                    const unsigned short* __restrict__ BT,
                                                    const unsigned char* __restrict__ packed,
                                                    const float* __restrict__ ratio_sel,
                                                    float* __restrict__ accum) {
    const int K = 512, NK = 8192;
    __shared__ union {
        unsigned short stage[2][2][8192];   // [dbuf][A/B][row*8 + kc16] 16B units; 2x32 KB
        float lg[128 * 132];                // 67.6 KB logit tile
    } sm;
    __shared__ float rsum[4];

    int m0 = blockIdx.x * 128, n0 = blockIdx.y * 128;
    int tid = threadIdx.x;
    int lane = tid & 63, wave = tid >> 6;
    int wm = wave >> 1, wn = wave & 1;
    int r = lane & 15, q = lane >> 4;

    f32x4 acc[4][4];
#pragma unroll
    for (int i = 0; i < 4; i++)
#pragma unroll
        for (int j = 0; j < 4; j++) acc[i][j] = (f32x4){0.f, 0.f, 0.f, 0.f};

    // LDS slot e (16B) of matrix X holds X[row=e>>3][K-chunk (e&7)^(row&7)]
    auto STAGE = [&](int buf, int kk) {
#pragma unroll
        for (int inst = 0; inst < 4; inst++) {
            int e = inst * 256 + tid;          // 0..1023
            int row = e >> 3;
            int sc = (e & 7) ^ (row & 7);      // inverse-swizzled source chunk
            gl_lds16(A + (size_t)(m0 + row) * K + kk + sc * 8,
                     (char*)sm.stage[buf][0] + e * 16);
        }
#pragma unroll
        for (int inst = 0; inst < 4; inst++) {
            int e = inst * 256 + tid;
            int row = e >> 3;
            int sc = (e & 7) ^ (row & 7);
            gl_lds16(BT + (size_t)(n0 + row) * K + kk + sc * 8,
                     (char*)sm.stage[buf][1] + e * 16);
        }
    };

    auto COMPUTE = [&](int buf) {
#pragma unroll
        for (int ks = 0; ks < 2; ks++) {
            bf16x8 a[4], b[4];
#pragma unroll
            for (int i = 0; i < 4; i++) {
                int row = wm * 64 + i * 16 + r;
                int c = (ks * 4 + q) ^ (r & 7);    // row&7 == r&7 here
                a[i] = *(const bf16x8*)((const char*)sm.stage[buf][0] + ((size_t)row * 8 + c) * 16);
            }
#pragma unroll
            for (int j = 0; j < 4; j++) {
                int row = wn * 64 + j * 16 + r;
                int c = (ks * 4 + q) ^ (r & 7);
                b[j] = *(const bf16x8*)((const char*)sm.stage[buf][1] + ((size_t)row * 8 + c) * 16);
            }
            __builtin_amdgcn_s_setprio(1);
#pragma unroll
            for (int i = 0; i < 4; i++)
#pragma unroll
                for (int j = 0; j < 4; j++)
                    acc[i][j] = __builtin_amdgcn_mfma_f32_16x16x32_bf16(a[i], b[j], acc[i][j], 0, 0, 0);
            __builtin_amdgcn_s_setprio(0);
        }
    };

    // prologue: two tiles in flight (16 loads/thread)
    STAGE(0, 0);
    STAGE(1, 64);
#pragma unroll
    for (int t = 0; t < 8; t++) {
        if (t < 7) { asm volatile("s_waitcnt vmcnt(8)" ::: "memory"); }   // oldest tile landed; next stays in flight
        else       { asm volatile("s_waitcnt vmcnt(0)" ::: "memory"); }
        __builtin_amdgcn_s_barrier();      // all waves: tile t visible
        COMPUTE(t & 1);
        __builtin_amdgcn_s_barrier();      // all waves done reading buf t&1
        if (t + 2 < 8) STAGE(t & 1, (t + 2) * 64);   // refill freed buffer
    }

    // ---- single-pass epilogue (lg overwrites stage: safe after final barrier) ----
#pragma unroll
    for (int i = 0; i < 4; i++)
#pragma unroll
        for (int j = 0; j < 4; j++)
#pragma unroll
            for (int reg = 0; reg < 4; reg++) {
                int row = wm * 64 + i * 16 + q * 4 + reg;
                int col = wn * 64 + j * 16 + r;
                sm.lg[row * 132 + col] = acc[i][j][reg];
            }
    __syncthreads();

    float lsum = 0.0f;
#pragma unroll
    for (int p = 0; p < 8; p++) {
        int idx = tid + p * 256;            // 2048 (b,k) pairs per block
        int bl = idx >> 7, kl = idx & 127;  // bl in [0,16)
        int b = (m0 >> 3) + bl;
        int k = n0 + kl;
        size_t pidx = (size_t)b * NK + k;

        int pk = packed[pidx];
        float rsl = ratio_sel[pidx];
        int tev = pk & 7;
        bool cen = (pk & 8) != 0;

        float L[8];
#pragma unroll
        for (int t = 0; t < 8; t++) L[t] = sm.lg[(bl * 8 + t) * 132 + kl];
        float mx = L[0];
#pragma unroll
        for (int t = 1; t < 8; t++) mx = fmaxf(mx, L[t]);
        float e[8], s = 0.0f;
#pragma unroll
        for (int t = 0; t < 8; t++) { e[t] = __expf(L[t] - mx); s += e[t]; }
        float inv = 1.0f / s;

        float cum = 0.0f, pte = 0.0f, ite = 0.0f;
#pragma unroll
        for (int t = 0; t < 8; t++) {
            float pt = e[t] * inv;
            float integ = 1.0f - cum;
            cum += pt;
            bool hit = (t == tev);
            pte = hit ? pt : pte;
            ite = hit ? integ : ite;
        }
        float ps  = fminf(fmaxf(pte, EPS), 1.0f - EPS);
        float is0 = fminf(fmaxf(ite, EPS), 1.0f - EPS);
        float isc = fminf(fmaxf(is0 - rsl * ps, EPS), 1.0f - EPS);
        float val = cen ? isc : ps;
        lsum += logf(val);
    }

    // block reduction (4 waves)
#pragma unroll
    for (int o = 32; o > 0; o >>= 1) lsum += __shfl_down(lsum, o);
    if (lane == 0) rsum[wave] = lsum;
    __syncthreads();
    if (tid == 0) {
        atomicAdd(&accum[0], rsum[0] + rsum[1] + rsum[2] + rsum[3]);
    }
}

__global__ void finalize_kernel(const float* __restrict__ accum, float* __restrict__ out) {
    out[0] = -accum[0] / (NUM_MARKED * H_T);
}

extern "C" void kernel_launch(void* const* d_in, const int* in_sizes, int n_in,
                              void* d_out, int out_size, void* d_ws, size_t ws_size,
                              hipStream_t stream) {
    const float* features = (const float*)d_in[0]; // 512x768
    const float* W1       = (const float*)d_in[1]; // 768x4096
    const float* b1       = (const float*)d_in[2]; // 4096
    const float* norm_w   = (const float*)d_in[3]; // 512
    const float* W2       = (const float*)d_in[4]; // 512x8192
    /* b2 (d_in[5]) is softmax(axis=1)-invariant: skipped */
    const int* is_event   = (const int*)d_in[6];   // 512x8x8192 (bool as i32)
    const int* is_cens    = (const int*)d_in[7];   // 512x8192  (bool as i32)
    const float* ratio    = (const float*)d_in[8]; // 512x8x8192
    float* out = (float*)d_out;

    char* ws = (char*)d_ws;
    size_t off = 0;
    auto alloc = [&](size_t bytes) { void* p = ws + off; off = (off + bytes + 255) & ~(size_t)255; return p; };
    unsigned short* W1T    = (unsigned short*)alloc((size_t)4096 * 768 * 2);
    unsigned short* W2T    = (unsigned short*)alloc((size_t)8192 * 512 * 2);
    unsigned short* featbf = (unsigned short*)alloc((size_t)512 * 768 * 2);
    float*          xbuf   = (float*)alloc((size_t)512 * 4096 * 4);
    unsigned short* xn     = (unsigned short*)alloc((size_t)4096 * 512 * 2);
    unsigned char*  packed = (unsigned char*)alloc((size_t)512 * 8192);
    float*          rsel   = (float*)alloc((size_t)512 * 8192 * 4);
    float*          accum  = (float*)alloc(64);

    prep_lite<<<960, 256, 0, stream>>>(features, W1, featbf, W1T, accum);
    mid_kernel<<<2560, 256, 0, stream>>>(featbf, W1T, b1, xbuf, W2, W2T,
                                         is_event, is_cens, ratio, packed, rsel);
    rms_kernel<<<4096, 256, 0, stream>>>(xbuf, norm_w, xn);
    gemm_loss<<<dim3(4096 / 128, 8192 / 128), 256, 0, stream>>>(xn, W2T, packed, rsel, accum);
    finalize_kernel<<<1, 1, 0, stream>>>(accum, out);
}

// Round 7
// 421.254 us; speedup vs baseline: 1.0514x; 1.0514x over previous
//
#include <hip/hip_runtime.h>
#include <hip/hip_bf16.h>
#include <cstdint>
#include <cstddef>

#define EPS 1e-8f
#define H_T 2.0794415416798357f /* ln(8) */
#define NUM_MARKED 4194304.0f   /* B*K: is_event is exactly one-hot over T */

typedef __attribute__((ext_vector_type(8))) short bf16x8;
typedef __attribute__((ext_vector_type(4))) float f32x4;

__device__ __forceinline__ unsigned short f2bf(float f) {
    union { float f; unsigned u; } v; v.f = f;
    unsigned r = v.u + 0x7fffu + ((v.u >> 16) & 1u);
    return (unsigned short)(r >> 16);
}

__device__ __forceinline__ void gl_lds16(const void* g, void* l) {
    __builtin_amdgcn_global_load_lds((const __attribute__((address_space(1))) unsigned int*)g,
                                     (__attribute__((address_space(3))) unsigned int*)l, 16, 0, 0);
}

// 64x64 f32->bf16 transpose tile. float4 loads, LDS [64][65], ushort4 stores.
__device__ __forceinline__ void transpose64(const float* __restrict__ in,
                                            unsigned short* __restrict__ out,
                                            int R, int C, int bx, int by,
                                            int tid, float* tile) {
    int c0 = bx * 64, r0 = by * 64;
    int row = tid >> 4, c4 = tid & 15;
#pragma unroll
    for (int i = 0; i < 4; i++) {
        float4 v = *(const float4*)(in + (size_t)(r0 + row + i * 16) * C + c0 + c4 * 4);
        float* t = tile + (row + i * 16) * 65 + c4 * 4;
        t[0] = v.x; t[1] = v.y; t[2] = v.z; t[3] = v.w;
    }
    __syncthreads();
    int rq = tid & 15, ccb = tid >> 4;
#pragma unroll
    for (int i = 0; i < 4; i++) {
        int cc = ccb + i * 16;
        ushort4 o;
        o.x = f2bf(tile[(rq * 4 + 0) * 65 + cc]);
        o.y = f2bf(tile[(rq * 4 + 1) * 65 + cc]);
        o.z = f2bf(tile[(rq * 4 + 2) * 65 + cc]);
        o.w = f2bf(tile[(rq * 4 + 3) * 65 + cc]);
        *(ushort4*)(out + (size_t)(c0 + cc) * R + r0 + rq * 4) = o;
    }
}

// ---------------- prep_lite: featbf + W1T ----------------
__global__ __launch_bounds__(256) void prep_lite(const float* __restrict__ features,
                                                 const float* __restrict__ W1,
                                                 unsigned short* __restrict__ featbf,
                                                 unsigned short* __restrict__ W1T,
                                                 float* __restrict__ accum) {
    __shared__ float tile[64 * 65];
    int bid = blockIdx.x, tid = threadIdx.x;
    if (bid < 192) {
        if (bid == 0 && tid < 8) accum[tid] = 0.0f;
        int i = (bid * 256 + tid) * 8;
        float4 a = *(const float4*)(features + i);
        float4 b = *(const float4*)(features + i + 4);
        ushort4 o0, o1;
        o0.x = f2bf(a.x); o0.y = f2bf(a.y); o0.z = f2bf(a.z); o0.w = f2bf(a.w);
        o1.x = f2bf(b.x); o1.y = f2bf(b.y); o1.z = f2bf(b.z); o1.w = f2bf(b.w);
        *(ushort4*)(featbf + i) = o0;
        *(ushort4*)(featbf + i + 4) = o1;
        return;
    }
    int b = bid - 192;
    transpose64(W1, W1T, 768, 4096, b & 63, b >> 6, tid, tile);
}

// ---------------- mid_kernel: GEMM1+bias || W2^T || compress stream ----------------
// grid: [0,512) gemm_bias | [512,1536) W2^T | [1536,5632) compress
// R7 compress: R5 block mapping (proven no-spill granularity: 4 k/thread),
// STATIC ev[8]/rt[8] arrays loaded up-front (no lambdas — R6's
// reference-captured lambda arrays spilled: VGPR 72, +47 MB scratch
// writes), __launch_bounds__(256,2) so the allocator may hold all 16
// loads in flight (R5's no-hint build chose VGPR=48 and serialized).
// W2^T moved BEFORE compress: transposes overlap under the stream
// instead of forming a serial tail.
__global__ __launch_bounds__(256, 2) void mid_kernel(const unsigned short* __restrict__ A,   // featbf 512x768
                                                     const unsigned short* __restrict__ BT,  // W1T 4096x768
                                                     const float* __restrict__ bias,         // b1
                                                     float* __restrict__ C,                  // xbuf 512x4096
                                                     const float* __restrict__ W2,
                                                     unsigned short* __restrict__ W2T,
                                                     const int* __restrict__ is_event,
                                                     const int* __restrict__ is_cens,
                                                     const float* __restrict__ ratio,
                                                     unsigned char* __restrict__ packed,
                                                     float* __restrict__ ratio_sel) {
    __shared__ union {
        struct { unsigned short lA[64 * 40]; unsigned short lB[64 * 40]; } g;
        float tile[64 * 65];
    } sm;
    int bid = blockIdx.x, tid = threadIdx.x;

    if (bid >= 1536) {
        // ---- compress: is_event one-hot over T -> packed(u8) + ratio_sel ----
        const int NK = 8192;
        int gid = (bid - 1536) * 256 + tid;        // [0, 1048576)
        int b = gid >> 11;
        int k0 = (gid & 2047) * 4;
        const int*   evp = is_event + (size_t)b * 8 * NK + k0;
        const float* rtp = ratio    + (size_t)b * 8 * NK + k0;

        // all 17 loads up-front, statically indexed (registers, not scratch)
        int4 ev[8]; float4 rt[8];
#pragma unroll
        for (int t = 0; t < 8; t++) ev[t] = *(const int4*)(evp + (size_t)t * NK);
#pragma unroll
        for (int t = 0; t < 8; t++) rt[t] = *(const float4*)(rtp + (size_t)t * NK);
        int4 c4 = *(const int4*)(is_cens + (size_t)b * NK + k0);

        int   tev[4]  = {0, 0, 0, 0};
        float rsl[4] = {0.f, 0.f, 0.f, 0.f};
#pragma unroll
        for (int t = 0; t < 8; t++) {
            int   vv[4] = {ev[t].x, ev[t].y, ev[t].z, ev[t].w};
            float rr[4] = {rt[t].x, rt[t].y, rt[t].z, rt[t].w};
#pragma unroll
            for (int j = 0; j < 4; j++) {
                bool e = vv[j] != 0;
                tev[j] = e ? t : tev[j];
                rsl[j] = e ? rr[j] : rsl[j];
            }
        }
        int cc[4] = {c4.x, c4.y, c4.z, c4.w};
        uchar4 pk4;
        pk4.x = (unsigned char)(tev[0] | ((cc[0] != 0) << 3));
        pk4.y = (unsigned char)(tev[1] | ((cc[1] != 0) << 3));
        pk4.z = (unsigned char)(tev[2] | ((cc[2] != 0) << 3));
        pk4.w = (unsigned char)(tev[3] | ((cc[3] != 0) << 3));
        *(uchar4*)(packed + (size_t)gid * 4) = pk4;
        float4 rs4; rs4.x = rsl[0]; rs4.y = rsl[1]; rs4.z = rsl[2]; rs4.w = rsl[3];
        *(float4*)(ratio_sel + (size_t)gid * 4) = rs4;
        return;
    }
    if (bid >= 512) {
        int b = bid - 512;
        transpose64(W2, W2T, 512, 8192, b & 127, b >> 7, tid, sm.tile);
        return;
    }

    // ---- gemm_bias: M=512, N=4096, K=768; 64x64 tile, 2x2 waves ----
    const int N = 4096, K = 768;
    int m0 = (bid & 7) * 64, n0 = (bid >> 3) * 64;
    int lane = tid & 63, wave = tid >> 6;
    int wm = wave >> 1, wn = wave & 1;
    int r = lane & 15, q = lane >> 4;

    f32x4 acc[2][2];
#pragma unroll
    for (int i = 0; i < 2; i++)
#pragma unroll
        for (int j = 0; j < 2; j++) acc[i][j] = (f32x4){0.f, 0.f, 0.f, 0.f};

    int ldrow = tid >> 2, ldc = (tid & 3) * 8;

    for (int kk = 0; kk < K; kk += 32) {
        uint4 av = *(const uint4*)(A + (size_t)(m0 + ldrow) * K + kk + ldc);
        uint4 bv = *(const uint4*)(BT + (size_t)(n0 + ldrow) * K + kk + ldc);
        __syncthreads();
        *(uint4*)(&sm.g.lA[ldrow * 40 + ldc]) = av;
        *(uint4*)(&sm.g.lB[ldrow * 40 + ldc]) = bv;
        __syncthreads();

        bf16x8 a0 = *(const bf16x8*)(&sm.g.lA[(wm * 32 + r) * 40 + q * 8]);
        bf16x8 a1 = *(const bf16x8*)(&sm.g.lA[(wm * 32 + 16 + r) * 40 + q * 8]);
        bf16x8 b0 = *(const bf16x8*)(&sm.g.lB[(wn * 32 + r) * 40 + q * 8]);
        bf16x8 b1 = *(const bf16x8*)(&sm.g.lB[(wn * 32 + 16 + r) * 40 + q * 8]);
        acc[0][0] = __builtin_amdgcn_mfma_f32_16x16x32_bf16(a0, b0, acc[0][0], 0, 0, 0);
        acc[0][1] = __builtin_amdgcn_mfma_f32_16x16x32_bf16(a0, b1, acc[0][1], 0, 0, 0);
        acc[1][0] = __builtin_amdgcn_mfma_f32_16x16x32_bf16(a1, b0, acc[1][0], 0, 0, 0);
        acc[1][1] = __builtin_amdgcn_mfma_f32_16x16x32_bf16(a1, b1, acc[1][1], 0, 0, 0);
    }

#pragma unroll
    for (int i = 0; i < 2; i++)
#pragma unroll
        for (int j = 0; j < 2; j++)
#pragma unroll
            for (int reg = 0; reg < 4; reg++) {
                int row = m0 + wm * 32 + i * 16 + q * 4 + reg;
                int col = n0 + wn * 32 + j * 16 + r;
                C[(size_t)row * N + col] = acc[i][j][reg] + bias[col];
            }
}

// ---------------- RMSNorm ----------------
__global__ __launch_bounds__(256) void rms_kernel(const float* __restrict__ x,
                                                  const float* __restrict__ norm_w,
                                                  unsigned short* __restrict__ xn) {
    int m = blockIdx.x;
    int tid = threadIdx.x;
    const float* row = x + (size_t)m * 512;
    float v0 = row[tid];
    float v1 = row[tid + 256];
    float ss = v0 * v0 + v1 * v1;
#pragma unroll
    for (int o = 32; o > 0; o >>= 1) ss += __shfl_down(ss, o);
    __shared__ float rs[4];
    __shared__ float scale_sh;
    int lane = tid & 63, wave = tid >> 6;
    if (lane == 0) rs[wave] = ss;
    __syncthreads();
    if (tid == 0) {
        float tot = rs[0] + rs[1] + rs[2] + rs[3];
        scale_sh = 1.0f / sqrtf(tot * (1.0f / 512.0f) + 1e-6f);
    }
    __syncthreads();
    float s = scale_sh;
    xn[(size_t)m * 512 + tid] = f2bf(v0 * s * norm_w[tid]);
    xn[(size_t)m * 512 + tid + 256] = f2bf(v1 * s * norm_w[tid + 256]);
}

// ---------------- GEMM2 + softmax/cumsum/loss, fused ----------------
// R5 structure (coalesced swizzled staging + counted-vmcnt depth-2
// pipeline + single-pass LDS epilogue) + R7: bijective XCD swizzle (T1)
// on a 1D grid of 2048 blocks (2048%8==0).
__global__ __launch_bounds__(256, 2) void gemm_loss(const unsigned short* __restrict__ A,
                                                    const unsigned short* __restrict__ BT,
                                                    const unsigned char* __restrict__ packed,
                                                    const float* __restrict__ ratio_sel,
                                                    float* __restrict__ accum) {
    const int K = 512, NK = 8192;
    __shared__ union {
        unsigned short stage[2][2][8192];   // [dbuf][A/B][row*8 + kc16] 16B units; 2x32 KB
        float lg[128 * 132];                // 67.6 KB logit tile
    } sm;
    __shared__ float rsum[4];

    // XCD-aware swizzle: consecutive lid2 within one XCD share A/B panels
    int lid = blockIdx.x;                       // [0, 2048)
    int lid2 = (lid & 7) * 256 + (lid >> 3);    // bijective (2048 % 8 == 0)
    int m0 = (lid2 & 31) * 128, n0 = (lid2 >> 5) * 128;

    int tid = threadIdx.x;
    int lane = tid & 63, wave = tid >> 6;
    int wm = wave >> 1, wn = wave & 1;
    int r = lane & 15, q = lane >> 4;

    f32x4 acc[4][4];
#pragma unroll
    for (int i = 0; i < 4; i++)
#pragma unroll
        for (int j = 0; j < 4; j++) acc[i][j] = (f32x4){0.f, 0.f, 0.f, 0.f};

    // LDS slot e (16B) of matrix X holds X[row=e>>3][K-chunk (e&7)^(row&7)]
    auto STAGE = [&](int buf, int kk) {
#pragma unroll
        for (int inst = 0; inst < 4; inst++) {
            int e = inst * 256 + tid;          // 0..1023
            int row = e >> 3;
            int sc = (e & 7) ^ (row & 7);      // inverse-swizzled source chunk
            gl_lds16(A + (size_t)(m0 + row) * K + kk + sc * 8,
                     (char*)sm.stage[buf][0] + e * 16);
        }
#pragma unroll
        for (int inst = 0; inst < 4; inst++) {
            int e = inst * 256 + tid;
            int row = e >> 3;
            int sc = (e & 7) ^ (row & 7);
            gl_lds16(BT + (size_t)(n0 + row) * K + kk + sc * 8,
                     (char*)sm.stage[buf][1] + e * 16);
        }
    };

    auto COMPUTE = [&](int buf) {
#pragma unroll
        for (int ks = 0; ks < 2; ks++) {
            bf16x8 a[4], b[4];
#pragma unroll
            for (int i = 0; i < 4; i++) {
                int row = wm * 64 + i * 16 + r;
                int c = (ks * 4 + q) ^ (r & 7);    // row&7 == r&7 here
                a[i] = *(const bf16x8*)((const char*)sm.stage[buf][0] + ((size_t)row * 8 + c) * 16);
            }
#pragma unroll
            for (int j = 0; j < 4; j++) {
                int row = wn * 64 + j * 16 + r;
                int c = (ks * 4 + q) ^ (r & 7);
                b[j] = *(const bf16x8*)((const char*)sm.stage[buf][1] + ((size_t)row * 8 + c) * 16);
            }
            __builtin_amdgcn_s_setprio(1);
#pragma unroll
            for (int i = 0; i < 4; i++)
#pragma unroll
                for (int j = 0; j < 4; j++)
                    acc[i][j] = __builtin_amdgcn_mfma_f32_16x16x32_bf16(a[i], b[j], acc[i][j], 0, 0, 0);
            __builtin_amdgcn_s_setprio(0);
        }
    };

    // prologue: two tiles in flight (16 loads/thread)
    STAGE(0, 0);
    STAGE(1, 64);
#pragma unroll
    for (int t = 0; t < 8; t++) {
        if (t < 7) { asm volatile("s_waitcnt vmcnt(8)" ::: "memory"); }   // oldest tile landed; next stays in flight
        else       { asm volatile("s_waitcnt vmcnt(0)" ::: "memory"); }
        __builtin_amdgcn_s_barrier();      // all waves: tile t visible
        COMPUTE(t & 1);
        __builtin_amdgcn_s_barrier();      // all waves done reading buf t&1
        if (t + 2 < 8) STAGE(t & 1, (t + 2) * 64);   // refill freed buffer
    }

    // ---- single-pass epilogue (lg overwrites stage: safe after final barrier) ----
#pragma unroll
    for (int i = 0; i < 4; i++)
#pragma unroll
        for (int j = 0; j < 4; j++)
#pragma unroll
            for (int reg = 0; reg < 4; reg++) {
                int row = wm * 64 + i * 16 + q * 4 + reg;
                int col = wn * 64 + j * 16 + r;
                sm.lg[row * 132 + col] = acc[i][j][reg];
            }
    __syncthreads();

    float lsum = 0.0f;
#pragma unroll
    for (int p = 0; p < 8; p++) {
        int idx = tid + p * 256;            // 2048 (b,k) pairs per block
        int bl = idx >> 7, kl = idx & 127;  // bl in [0,16)
        int b = (m0 >> 3) + bl;
        int k = n0 + kl;
        size_t pidx = (size_t)b * NK + k;

        int pk = packed[pidx];
        float rsl = ratio_sel[pidx];
        int tev = pk & 7;
        bool cen = (pk & 8) != 0;

        float L[8];
#pragma unroll
        for (int t = 0; t < 8; t++) L[t] = sm.lg[(bl * 8 + t) * 132 + kl];
        float mx = L[0];
#pragma unroll
        for (int t = 1; t < 8; t++) mx = fmaxf(mx, L[t]);
        float e[8], s = 0.0f;
#pragma unroll
        for (int t = 0; t < 8; t++) { e[t] = __expf(L[t] - mx); s += e[t]; }
        float inv = 1.0f / s;

        float cum = 0.0f, pte = 0.0f, ite = 0.0f;
#pragma unroll
        for (int t = 0; t < 8; t++) {
            float pt = e[t] * inv;
            float integ = 1.0f - cum;
            cum += pt;
            bool hit = (t == tev);
            pte = hit ? pt : pte;
            ite = hit ? integ : ite;
        }
        float ps  = fminf(fmaxf(pte, EPS), 1.0f - EPS);
        float is0 = fminf(fmaxf(ite, EPS), 1.0f - EPS);
        float isc = fminf(fmaxf(is0 - rsl * ps, EPS), 1.0f - EPS);
        float val = cen ? isc : ps;
        lsum += logf(val);
    }

    // block reduction (4 waves)
#pragma unroll
    for (int o = 32; o > 0; o >>= 1) lsum += __shfl_down(lsum, o);
    if (lane == 0) rsum[wave] = lsum;
    __syncthreads();
    if (tid == 0) {
        atomicAdd(&accum[0], rsum[0] + rsum[1] + rsum[2] + rsum[3]);
    }
}

__global__ void finalize_kernel(const float* __restrict__ accum, float* __restrict__ out) {
    out[0] = -accum[0] / (NUM_MARKED * H_T);
}

extern "C" void kernel_launch(void* const* d_in, const int* in_sizes, int n_in,
                              void* d_out, int out_size, void* d_ws, size_t ws_size,
                              hipStream_t stream) {
    const float* features = (const float*)d_in[0]; // 512x768
    const float* W1       = (const float*)d_in[1]; // 768x4096
    const float* b1       = (const float*)d_in[2]; // 4096
    const float* norm_w   = (const float*)d_in[3]; // 512
    const float* W2       = (const float*)d_in[4]; // 512x8192
    /* b2 (d_in[5]) is softmax(axis=1)-invariant: skipped */
    const int* is_event   = (const int*)d_in[6];   // 512x8x8192 (bool as i32)
    const int* is_cens    = (const int*)d_in[7];   // 512x8192  (bool as i32)
    const float* ratio    = (const float*)d_in[8]; // 512x8x8192
    float* out = (float*)d_out;

    char* ws = (char*)d_ws;
    size_t off = 0;
    auto alloc = [&](size_t bytes) { void* p = ws + off; off = (off + bytes + 255) & ~(size_t)255; return p; };
    unsigned short* W1T    = (unsigned short*)alloc((size_t)4096 * 768 * 2);
    unsigned short* W2T    = (unsigned short*)alloc((size_t)8192 * 512 * 2);
    unsigned short* featbf = (unsigned short*)alloc((size_t)512 * 768 * 2);
    float*          xbuf   = (float*)alloc((size_t)512 * 4096 * 4);
    unsigned short* xn     = (unsigned short*)alloc((size_t)4096 * 512 * 2);
    unsigned char*  packed = (unsigned char*)alloc((size_t)512 * 8192);
    float*          rsel   = (float*)alloc((size_t)512 * 8192 * 4);
    float*          accum  = (float*)alloc(64);

    prep_lite<<<960, 256, 0, stream>>>(features, W1, featbf, W1T, accum);
    mid_kernel<<<5632, 256, 0, stream>>>(featbf, W1T, b1, xbuf, W2, W2T,
                                         is_event, is_cens, ratio, packed, rsel);
    rms_kernel<<<4096, 256, 0, stream>>>(xbuf, norm_w, xn);
    gemm_loss<<<2048, 256, 0, stream>>>(xn, W2T, packed, rsel, accum);
    finalize_kernel<<<1, 1, 0, stream>>>(accum, out);
}

// Round 9
// 406.246 us; speedup vs baseline: 1.0903x; 1.0369x over previous
//
#include <hip/hip_runtime.h>
#include <hip/hip_bf16.h>
#include <cstdint>
#include <cstddef>

#define EPS 1e-8f
#define H_T 2.0794415416798357f /* ln(8) */
#define NUM_MARKED 4194304.0f   /* B*K: is_event is exactly one-hot over T */

typedef __attribute__((ext_vector_type(8))) short bf16x8;
typedef __attribute__((ext_vector_type(4))) float f32x4;

__device__ __forceinline__ unsigned short f2bf(float f) {
    union { float f; unsigned u; } v; v.f = f;
    unsigned r = v.u + 0x7fffu + ((v.u >> 16) & 1u);
    return (unsigned short)(r >> 16);
}

__device__ __forceinline__ void gl_lds16(const void* g, void* l) {
    __builtin_amdgcn_global_load_lds((const __attribute__((address_space(1))) unsigned int*)g,
                                     (__attribute__((address_space(3))) unsigned int*)l, 16, 0, 0);
}

// 64x64 f32->bf16 transpose tile. float4 loads, LDS [64][65], ushort4 stores.
__device__ __forceinline__ void transpose64(const float* __restrict__ in,
                                            unsigned short* __restrict__ out,
                                            int R, int C, int bx, int by,
                                            int tid, float* tile) {
    int c0 = bx * 64, r0 = by * 64;
    int row = tid >> 4, c4 = tid & 15;
#pragma unroll
    for (int i = 0; i < 4; i++) {
        float4 v = *(const float4*)(in + (size_t)(r0 + row + i * 16) * C + c0 + c4 * 4);
        float* t = tile + (row + i * 16) * 65 + c4 * 4;
        t[0] = v.x; t[1] = v.y; t[2] = v.z; t[3] = v.w;
    }
    __syncthreads();
    int rq = tid & 15, ccb = tid >> 4;
#pragma unroll
    for (int i = 0; i < 4; i++) {
        int cc = ccb + i * 16;
        ushort4 o;
        o.x = f2bf(tile[(rq * 4 + 0) * 65 + cc]);
        o.y = f2bf(tile[(rq * 4 + 1) * 65 + cc]);
        o.z = f2bf(tile[(rq * 4 + 2) * 65 + cc]);
        o.w = f2bf(tile[(rq * 4 + 3) * 65 + cc]);
        *(ushort4*)(out + (size_t)(c0 + cc) * R + r0 + rq * 4) = o;
    }
}

// ---------------- prep_lite: featbf + W1T ----------------
__global__ __launch_bounds__(256) void prep_lite(const float* __restrict__ features,
                                                 const float* __restrict__ W1,
                                                 unsigned short* __restrict__ featbf,
                                                 unsigned short* __restrict__ W1T,
                                                 float* __restrict__ accum) {
    __shared__ float tile[64 * 65];
    int bid = blockIdx.x, tid = threadIdx.x;
    if (bid < 192) {
        if (bid == 0 && tid < 8) accum[tid] = 0.0f;
        int i = (bid * 256 + tid) * 8;
        float4 a = *(const float4*)(features + i);
        float4 b = *(const float4*)(features + i + 4);
        ushort4 o0, o1;
        o0.x = f2bf(a.x); o0.y = f2bf(a.y); o0.z = f2bf(a.z); o0.w = f2bf(a.w);
        o1.x = f2bf(b.x); o1.y = f2bf(b.y); o1.z = f2bf(b.z); o1.w = f2bf(b.w);
        *(ushort4*)(featbf + i) = o0;
        *(ushort4*)(featbf + i + 4) = o1;
        return;
    }
    int b = bid - 192;
    transpose64(W1, W1T, 768, 4096, b & 63, b >> 6, tid, tile);
}

// ---------------- mid_kernel: GEMM1+bias || W2^T ----------------
// grid: [0,512) gemm_bias | [512,1536) W2^T  (compress lives in gemm_loss now)
__global__ __launch_bounds__(256) void mid_kernel(const unsigned short* __restrict__ A,   // featbf 512x768
                                                  const unsigned short* __restrict__ BT,  // W1T 4096x768
                                                  const float* __restrict__ bias,         // b1
                                                  float* __restrict__ C,                  // xbuf 512x4096
                                                  const float* __restrict__ W2,
                                                  unsigned short* __restrict__ W2T) {
    __shared__ union {
        struct { unsigned short lA[64 * 40]; unsigned short lB[64 * 40]; } g;
        float tile[64 * 65];
    } sm;
    int bid = blockIdx.x, tid = threadIdx.x;

    if (bid >= 512) {
        int b = bid - 512;
        transpose64(W2, W2T, 512, 8192, b & 127, b >> 7, tid, sm.tile);
        return;
    }

    // ---- gemm_bias: M=512, N=4096, K=768; 64x64 tile, 2x2 waves ----
    const int N = 4096, K = 768;
    int m0 = (bid & 7) * 64, n0 = (bid >> 3) * 64;
    int lane = tid & 63, wave = tid >> 6;
    int wm = wave >> 1, wn = wave & 1;
    int r = lane & 15, q = lane >> 4;

    f32x4 acc[2][2];
#pragma unroll
    for (int i = 0; i < 2; i++)
#pragma unroll
        for (int j = 0; j < 2; j++) acc[i][j] = (f32x4){0.f, 0.f, 0.f, 0.f};

    int ldrow = tid >> 2, ldc = (tid & 3) * 8;

    for (int kk = 0; kk < K; kk += 32) {
        uint4 av = *(const uint4*)(A + (size_t)(m0 + ldrow) * K + kk + ldc);
        uint4 bv = *(const uint4*)(BT + (size_t)(n0 + ldrow) * K + kk + ldc);
        __syncthreads();
        *(uint4*)(&sm.g.lA[ldrow * 40 + ldc]) = av;
        *(uint4*)(&sm.g.lB[ldrow * 40 + ldc]) = bv;
        __syncthreads();

        bf16x8 a0 = *(const bf16x8*)(&sm.g.lA[(wm * 32 + r) * 40 + q * 8]);
        bf16x8 a1 = *(const bf16x8*)(&sm.g.lA[(wm * 32 + 16 + r) * 40 + q * 8]);
        bf16x8 b0 = *(const bf16x8*)(&sm.g.lB[(wn * 32 + r) * 40 + q * 8]);
        bf16x8 b1 = *(const bf16x8*)(&sm.g.lB[(wn * 32 + 16 + r) * 40 + q * 8]);
        acc[0][0] = __builtin_amdgcn_mfma_f32_16x16x32_bf16(a0, b0, acc[0][0], 0, 0, 0);
        acc[0][1] = __builtin_amdgcn_mfma_f32_16x16x32_bf16(a0, b1, acc[0][1], 0, 0, 0);
        acc[1][0] = __builtin_amdgcn_mfma_f32_16x16x32_bf16(a1, b0, acc[1][0], 0, 0, 0);
        acc[1][1] = __builtin_amdgcn_mfma_f32_16x16x32_bf16(a1, b1, acc[1][1], 0, 0, 0);
    }

#pragma unroll
    for (int i = 0; i < 2; i++)
#pragma unroll
        for (int j = 0; j < 2; j++)
#pragma unroll
            for (int reg = 0; reg < 4; reg++) {
                int row = m0 + wm * 32 + i * 16 + q * 4 + reg;
                int col = n0 + wn * 32 + j * 16 + r;
                C[(size_t)row * N + col] = acc[i][j][reg] + bias[col];
            }
}

// ---------------- RMSNorm ----------------
__global__ __launch_bounds__(256) void rms_kernel(const float* __restrict__ x,
                                                  const float* __restrict__ norm_w,
                                                  unsigned short* __restrict__ xn) {
    int m = blockIdx.x;
    int tid = threadIdx.x;
    const float* row = x + (size_t)m * 512;
    float v0 = row[tid];
    float v1 = row[tid + 256];
    float ss = v0 * v0 + v1 * v1;
#pragma unroll
    for (int o = 32; o > 0; o >>= 1) ss += __shfl_down(ss, o);
    __shared__ float rs[4];
    __shared__ float scale_sh;
    int lane = tid & 63, wave = tid >> 6;
    if (lane == 0) rs[wave] = ss;
    __syncthreads();
    if (tid == 0) {
        float tot = rs[0] + rs[1] + rs[2] + rs[3];
        scale_sh = 1.0f / sqrtf(tot * (1.0f / 512.0f) + 1e-6f);
    }
    __syncthreads();
    float s = scale_sh;
    xn[(size_t)m * 512 + tid] = f2bf(v0 * s * norm_w[tid]);
    xn[(size_t)m * 512 + tid + 256] = f2bf(v1 * s * norm_w[tid + 256]);
}

// ---------------- GEMM2 + compress pre-phase + softmax/cumsum/loss ----------------
// M=4096, N=8192, K=512. BM=BN=128, BK=64, 256 threads = 4 waves (2x2).
// R9 (R8 post-mortem): the fused compress is now a SELF-CONTAINED pre-phase
// with ordinary compiler-managed loads -> cpk/csel LDS, followed by an
// explicit vmcnt(0) drain. The counted tile pipeline below is then
// byte-identical to R5's proven one and starts from a known-zero VMEM
// queue — no hand-counting across compiler-scheduled register loads
// (R8's mixed-stream counts broke: any spill/reorder shifts the queue ->
// half-staged tiles -> absmax 2.3). Hiding of the compress stream comes
// from inter-block overlap (2 blocks/CU; m114: one block's stream runs
// under the other's stall-heavy GEMM pipeline).
__global__ __launch_bounds__(256, 2) void gemm_loss(const unsigned short* __restrict__ A,
                                                    const unsigned short* __restrict__ BT,
                                                    const int* __restrict__ is_event,
                                                    const int* __restrict__ is_cens,
                                                    const float* __restrict__ ratio,
                                                    float* __restrict__ accum) {
    const int K = 512, NK = 8192;
    __shared__ union {
        unsigned short stage[2][2][8192];   // [dbuf][A/B][row*8 + kc16] 16B units; 2x32 KB
        float lg[128 * 132];                // 67.6 KB logit tile (R5 epilogue layout)
    } sm;
    __shared__ float csel[2048];            // 8 KB : selected ratio per (bl,kl)
    __shared__ unsigned short cpk[2048];    // 4 KB : t_event | cen<<3
    __shared__ float rsum[4];

    int m0 = blockIdx.x * 128, n0 = blockIdx.y * 128;
    int tid = threadIdx.x;
    int lane = tid & 63, wave = tid >> 6;
    int wm = wave >> 1, wn = wave & 1;
    int r = lane & 15, q = lane >> 4;

    // ---- compress pre-phase: thread owns (bl = tid>>4, kl = (tid&15)*8 .. +7) ----
    {
        int blw = tid >> 4;
        int klo = (tid & 15) * 8;
        size_t bg = (size_t)((m0 >> 3) + blw);
        const int*   evp = is_event + bg * 8 * NK + n0 + klo;
        const float* rtp = ratio    + bg * 8 * NK + n0 + klo;
        const int*   cnp = is_cens  + bg * NK + n0 + klo;

        int tevr[8]; float rslr[8];
#pragma unroll
        for (int j = 0; j < 8; j++) { tevr[j] = 0; rslr[j] = 0.0f; }
        int4 cen0 = *(const int4*)(cnp);
        int4 cen1 = *(const int4*)(cnp + 4);
#pragma unroll
        for (int t = 0; t < 8; t++) {
            int4   e0 = *(const int4*)(evp + (size_t)t * NK);
            int4   e1 = *(const int4*)(evp + (size_t)t * NK + 4);
            float4 r0 = *(const float4*)(rtp + (size_t)t * NK);
            float4 r1 = *(const float4*)(rtp + (size_t)t * NK + 4);
            int   vv[8] = {e0.x, e0.y, e0.z, e0.w, e1.x, e1.y, e1.z, e1.w};
            float rr[8] = {r0.x, r0.y, r0.z, r0.w, r1.x, r1.y, r1.z, r1.w};
#pragma unroll
            for (int j = 0; j < 8; j++) {
                bool e = vv[j] != 0;
                tevr[j] = e ? t : tevr[j];
                rslr[j] = e ? rr[j] : rslr[j];
            }
        }
        int cenb[8];
        cenb[0] = cen0.x != 0; cenb[1] = cen0.y != 0; cenb[2] = cen0.z != 0; cenb[3] = cen0.w != 0;
        cenb[4] = cen1.x != 0; cenb[5] = cen1.y != 0; cenb[6] = cen1.z != 0; cenb[7] = cen1.w != 0;
#pragma unroll
        for (int j = 0; j < 8; j++) {
            int p = blw * 128 + klo + j;
            cpk[p]  = (unsigned short)(tevr[j] | (cenb[j] << 3));
            csel[p] = rslr[j];
        }
    }
    // drain ALL compress VMEM so the counted pipeline starts from vmcnt=0
    asm volatile("s_waitcnt vmcnt(0)" ::: "memory");

    f32x4 acc[4][4];
#pragma unroll
    for (int i = 0; i < 4; i++)
#pragma unroll
        for (int j = 0; j < 4; j++) acc[i][j] = (f32x4){0.f, 0.f, 0.f, 0.f};

    // LDS slot e (16B) of matrix X holds X[row=e>>3][K-chunk (e&7)^(row&7)]
    auto STAGE = [&](int buf, int kk) {
#pragma unroll
        for (int inst = 0; inst < 4; inst++) {
            int e = inst * 256 + tid;
            int row = e >> 3;
            int sc = (e & 7) ^ (row & 7);
            gl_lds16(A + (size_t)(m0 + row) * K + kk + sc * 8,
                     (char*)sm.stage[buf][0] + e * 16);
        }
#pragma unroll
        for (int inst = 0; inst < 4; inst++) {
            int e = inst * 256 + tid;
            int row = e >> 3;
            int sc = (e & 7) ^ (row & 7);
            gl_lds16(BT + (size_t)(n0 + row) * K + kk + sc * 8,
                     (char*)sm.stage[buf][1] + e * 16);
        }
    };

    auto COMPUTE = [&](int buf) {
#pragma unroll
        for (int ks = 0; ks < 2; ks++) {
            bf16x8 a[4], b[4];
#pragma unroll
            for (int i = 0; i < 4; i++) {
                int row = wm * 64 + i * 16 + r;
                int c = (ks * 4 + q) ^ (r & 7);
                a[i] = *(const bf16x8*)((const char*)sm.stage[buf][0] + ((size_t)row * 8 + c) * 16);
            }
#pragma unroll
            for (int j = 0; j < 4; j++) {
                int row = wn * 64 + j * 16 + r;
                int c = (ks * 4 + q) ^ (r & 7);
                b[j] = *(const bf16x8*)((const char*)sm.stage[buf][1] + ((size_t)row * 8 + c) * 16);
            }
            __builtin_amdgcn_s_setprio(1);
#pragma unroll
            for (int i = 0; i < 4; i++)
#pragma unroll
                for (int j = 0; j < 4; j++)
                    acc[i][j] = __builtin_amdgcn_mfma_f32_16x16x32_bf16(a[i], b[j], acc[i][j], 0, 0, 0);
            __builtin_amdgcn_s_setprio(0);
        }
    };

    // prologue: two tiles in flight (16 gl_lds/thread) — R5-proven counts
    STAGE(0, 0);
    STAGE(1, 64);
#pragma unroll
    for (int t = 0; t < 8; t++) {
        if (t < 7) { asm volatile("s_waitcnt vmcnt(8)" ::: "memory"); }
        else       { asm volatile("s_waitcnt vmcnt(0)" ::: "memory"); }
        __builtin_amdgcn_s_barrier();      // tile t visible to all waves
        COMPUTE(t & 1);
        __builtin_amdgcn_s_barrier();      // all waves done reading buf t&1
        if (t + 2 < 8) STAGE(t & 1, (t + 2) * 64);
    }

    // ---- single-pass epilogue (lg overwrites stage: safe after final barrier) ----
#pragma unroll
    for (int i = 0; i < 4; i++)
#pragma unroll
        for (int j = 0; j < 4; j++)
#pragma unroll
            for (int reg = 0; reg < 4; reg++) {
                int row = wm * 64 + i * 16 + q * 4 + reg;
                int col = wn * 64 + j * 16 + r;
                sm.lg[row * 132 + col] = acc[i][j][reg];
            }
    __syncthreads();

    float lsum = 0.0f;
#pragma unroll
    for (int p = 0; p < 8; p++) {
        int idx = tid + p * 256;            // 2048 (b,k) pairs per block
        int bl = idx >> 7, kl = idx & 127;

        int pk = cpk[idx];
        float rsl = csel[idx];
        int tev = pk & 7;
        bool cen = (pk & 8) != 0;

        float L[8];
#pragma unroll
        for (int t = 0; t < 8; t++) L[t] = sm.lg[(bl * 8 + t) * 132 + kl];
        float mx = L[0];
#pragma unroll
        for (int t = 1; t < 8; t++) mx = fmaxf(mx, L[t]);
        float e[8], s = 0.0f;
#pragma unroll
        for (int t = 0; t < 8; t++) { e[t] = __expf(L[t] - mx); s += e[t]; }
        float inv = 1.0f / s;

        float cum = 0.0f, pte = 0.0f, ite = 0.0f;
#pragma unroll
        for (int t = 0; t < 8; t++) {
            float pt = e[t] * inv;
            float integ = 1.0f - cum;
            cum += pt;
            bool hit = (t == tev);
            pte = hit ? pt : pte;
            ite = hit ? integ : ite;
        }
        float ps  = fminf(fmaxf(pte, EPS), 1.0f - EPS);
        float is0 = fminf(fmaxf(ite, EPS), 1.0f - EPS);
        float isc = fminf(fmaxf(is0 - rsl * ps, EPS), 1.0f - EPS);
        float val = cen ? isc : ps;
        lsum += logf(val);
    }

    // block reduction (4 waves)
#pragma unroll
    for (int o = 32; o > 0; o >>= 1) lsum += __shfl_down(lsum, o);
    if (lane == 0) rsum[wave] = lsum;
    __syncthreads();
    if (tid == 0) {
        atomicAdd(&accum[0], rsum[0] + rsum[1] + rsum[2] + rsum[3]);
    }
}

__global__ void finalize_kernel(const float* __restrict__ accum, float* __restrict__ out) {
    out[0] = -accum[0] / (NUM_MARKED * H_T);
}

extern "C" void kernel_launch(void* const* d_in, const int* in_sizes, int n_in,
                              void* d_out, int out_size, void* d_ws, size_t ws_size,
                              hipStream_t stream) {
    const float* features = (const float*)d_in[0]; // 512x768
    const float* W1       = (const float*)d_in[1]; // 768x4096
    const float* b1       = (const float*)d_in[2]; // 4096
    const float* norm_w   = (const float*)d_in[3]; // 512
    const float* W2       = (const float*)d_in[4]; // 512x8192
    /* b2 (d_in[5]) is softmax(axis=1)-invariant: skipped */
    const int* is_event   = (const int*)d_in[6];   // 512x8x8192 (bool as i32)
    const int* is_cens    = (const int*)d_in[7];   // 512x8192  (bool as i32)
    const float* ratio    = (const float*)d_in[8]; // 512x8x8192
    float* out = (float*)d_out;

    char* ws = (char*)d_ws;
    size_t off = 0;
    auto alloc = [&](size_t bytes) { void* p = ws + off; off = (off + bytes + 255) & ~(size_t)255; return p; };
    unsigned short* W1T    = (unsigned short*)alloc((size_t)4096 * 768 * 2);
    unsigned short* W2T    = (unsigned short*)alloc((size_t)8192 * 512 * 2);
    unsigned short* featbf = (unsigned short*)alloc((size_t)512 * 768 * 2);
    float*          xbuf   = (float*)alloc((size_t)512 * 4096 * 4);
    unsigned short* xn     = (unsigned short*)alloc((size_t)4096 * 512 * 2);
    float*          accum  = (float*)alloc(64);

    prep_lite<<<960, 256, 0, stream>>>(features, W1, featbf, W1T, accum);
    mid_kernel<<<1536, 256, 0, stream>>>(featbf, W1T, b1, xbuf, W2, W2T);
    rms_kernel<<<4096, 256, 0, stream>>>(xbuf, norm_w, xn);
    gemm_loss<<<dim3(4096 / 128, 8192 / 128), 256, 0, stream>>>(xn, W2T, is_event, is_cens, ratio, accum);
    finalize_kernel<<<1, 1, 0, stream>>>(accum, out);
}